// Round 7
// baseline (5002.196 us; speedup 1.0000x reference)
//
#include <hip/hip_runtime.h>
#include <math.h>

#define TT 400
#define BBATCH 256
#define VDIM 128
#define CDIM 64
#define HDIM 512
#define KB 64
#define NCHUNK 11

typedef double d4 __attribute__((ext_vector_type(4)));

__device__ __forceinline__ double sigd(double x) {
  if (x >= 0.0) { double e = exp(-x); return 1.0 / (1.0 + e); }
  double e = exp(x); return e / (1.0 + e);
}

// transpose W_out/W_ctrl to [k][c]; init rowlive/alive. All other state is
// (re)initialized inside the step kernels via t==0 guards.
__global__ __launch_bounds__(256) void k_init(
    float* __restrict__ wtro, const float* __restrict__ W_out,
    float* __restrict__ wtrc, const float* __restrict__ W_ctrl,
    int* __restrict__ rowlive, int* __restrict__ alive)
{
  const int i = blockIdx.x * 256 + threadIdx.x;
  if (i < HDIM * CDIM) {
    const int k = i >> 6, c = i & 63;
    wtro[i] = W_out[c * HDIM + k];
  }
  if (i < 577 * CDIM) {
    const int k = i >> 6, c = i & 63;
    wtrc[i] = W_ctrl[c * 577 + k];
  }
  if (i < BBATCH) rowlive[i] = 1;
  if (i < TT) alive[i] = 0;
}

// Phase 1: gates GEMM (f64 MFMA) + fused LSTM cell.
// Grid (64, 8): 64 col-blocks (8 hidden x 4 gates) x 8 row-blocks of 32 rows.
// KB=64 k-chunks: 11 barriers instead of 22. ~74 KB LDS -> 2 blocks/CU.
__global__ __launch_bounds__(256) void k_phase1(
    const float* __restrict__ X, const float* __restrict__ W_ih,
    const float* __restrict__ W_hh, const float* __restrict__ b_ih,
    const float* __restrict__ b_hh, const double* __restrict__ hR,
    double* __restrict__ hW, double* __restrict__ cst,
    const double* __restrict__ ybar, const int* __restrict__ rowlive,
    const int* __restrict__ alive, int t)
{
  if (t > 0 && alive[t - 1] == 0) return;      // everything halted: dead step

  const int tid  = threadIdx.x;
  const int lane = tid & 63;
  const int wid  = tid >> 6;
  const int cb   = blockIdx.x;
  const int rb   = blockIdx.y;
  const int r0   = rb * 32;
  const int hbase = cb * 8;

  // 32-row block skip: all rows halted -> no output of this block is ever read
  if (t > 0) {
    const unsigned long long m =
        __ballot((lane < 32) && (rowlive[r0 + (lane & 31)] != 0));
    if (m == 0ull) return;
  }

  // fragment staging; k-slot stride padded 64->66 to break write bank conflicts
  __shared__ __align__(16) double aF[2][2][16][66];   // 33.8 KB
  __shared__ __align__(16) double bF[2][2][16][66];   // 33.8 KB
  __shared__ __align__(16) double g_s[32][33];        //  8.4 KB

  const int sk  = (tid & 7) * 4;    // k offset within 32-k half-chunk
  const int sr  = tid >> 3;         // 0..31: A-row / B-col
  const int s0  = sk >> 2;          // k-slot 0..7 (half 0); half 1 = +8
  const int srt = sr >> 4, srr = sr & 15;
  const int wg  = (sr >> 3) * HDIM + hbase + (sr & 7);  // W row for col sr

  // Empirical f64-MFMA D-layout probe: A[i][0]=i+1,A[i][1]=1,B[0][j]=1,
  // B[1][j]=1000(j+1) => D[i][j]=(i+1)+1000(j+1); decode reg->row/col.
  int rowm[4], colm[4];
  {
    d4 dp = {0.0, 0.0, 0.0, 0.0};
    const double ap = (lane < 16) ? (double)(lane + 1) : (lane < 32 ? 1.0 : 0.0);
    const double bp = (lane < 16) ? 1.0
                    : (lane < 32 ? 1000.0 * (double)((lane & 15) + 1) : 0.0);
    dp = __builtin_amdgcn_mfma_f64_16x16x4f64(ap, bp, dp, 0, 0, 0);
    #pragma unroll
    for (int r = 0; r < 4; ++r) {
      const int iv = (int)(dp[r] + 0.5);
      rowm[r] = ((iv % 1000) - 1) & 15;
      colm[r] = ((iv / 1000) - 1) & 15;
    }
  }

  double pa[2][4];
  float  pw[2][4];

  auto load_chunk = [&](int ci) {
    const int rr = r0 + sr;
    #pragma unroll
    for (int g = 0; g < 2; ++g) {
      const int kk = ci * KB + sk + 32 * g;
      if (kk < VDIM) {
        const float4 v = *(const float4*)(X + ((size_t)t * BBATCH + rr) * VDIM + kk);
        pa[g][0] = v.x; pa[g][1] = v.y; pa[g][2] = v.z; pa[g][3] = v.w;
      } else if (t == 0) {
        pa[g][0] = 0.0; pa[g][1] = 0.0; pa[g][2] = 0.0; pa[g][3] = 0.0;
      } else if (kk < VDIM + CDIM) {
        const double2 v0 = *(const double2*)(ybar + (size_t)rr * CDIM + (kk - VDIM));
        const double2 v1 = *(const double2*)(ybar + (size_t)rr * CDIM + (kk - VDIM) + 2);
        pa[g][0] = v0.x; pa[g][1] = v0.y; pa[g][2] = v1.x; pa[g][3] = v1.y;
      } else {
        const double2 v0 = *(const double2*)(hR + (size_t)rr * HDIM + (kk - 192));
        const double2 v1 = *(const double2*)(hR + (size_t)rr * HDIM + (kk - 192) + 2);
        pa[g][0] = v0.x; pa[g][1] = v0.y; pa[g][2] = v1.x; pa[g][3] = v1.y;
      }
      const float4 wv = (kk < 192)
        ? *(const float4*)(W_ih + (size_t)wg * 192 + kk)
        : *(const float4*)(W_hh + (size_t)wg * HDIM + (kk - 192));
      pw[g][0] = wv.x; pw[g][1] = wv.y; pw[g][2] = wv.z; pw[g][3] = wv.w;
    }
  };
  auto store_chunk = [&](int buf) {
    #pragma unroll
    for (int g = 0; g < 2; ++g) {
      const int s = s0 + 8 * g;
      #pragma unroll
      for (int j = 0; j < 4; ++j)
        aF[buf][srt][s][16 * j + srr] = pa[g][j];
      #pragma unroll
      for (int j = 0; j < 4; ++j)
        bF[buf][srt][s][16 * j + srr] = (double)pw[g][j];
    }
  };

  const int rt = wid >> 1, ct = wid & 1;   // wave's 16x16 output tile
  d4 aa = {0.0, 0.0, 0.0, 0.0}, ab = aa;

  load_chunk(0);
  store_chunk(0);
  __syncthreads();

  // single barrier per chunk: store(p^1) races only with reads of p^1 in the
  // PREVIOUS iteration, which the previous barrier already ordered.
  for (int ci = 0; ci < NCHUNK; ++ci) {
    const int p = ci & 1;
    if (ci + 1 < NCHUNK) load_chunk(ci + 1);
    #pragma unroll
    for (int ss = 0; ss < 16; ++ss) {
      const double av = aF[p][rt][ss][lane];
      const double bv = bF[p][ct][ss][lane];
      if (ss & 1) ab = __builtin_amdgcn_mfma_f64_16x16x4f64(av, bv, ab, 0, 0, 0);
      else        aa = __builtin_amdgcn_mfma_f64_16x16x4f64(av, bv, aa, 0, 0, 0);
    }
    if (ci + 1 < NCHUNK) store_chunk(p ^ 1);
    __syncthreads();
  }
  const d4 acc = aa + ab;

  #pragma unroll
  for (int r = 0; r < 4; ++r)
    g_s[16 * rt + rowm[r]][16 * ct + colm[r]] = acc[r];
  __syncthreads();

  // LSTM cell: 32 rows x 8 hidden = 256 pairs, 1/thread; 8 consecutive lanes
  // = 8 consecutive hidden units -> 64B-contiguous global accesses.
  {
    const int jj = tid & 7, r = tid >> 3;
    const int g0 = hbase + jj;
    const double gi = g_s[r][jj]      + (double)b_ih[0 * HDIM + g0] + (double)b_hh[0 * HDIM + g0];
    const double gf = g_s[r][8 + jj]  + (double)b_ih[1 * HDIM + g0] + (double)b_hh[1 * HDIM + g0];
    const double gg = g_s[r][16 + jj] + (double)b_ih[2 * HDIM + g0] + (double)b_hh[2 * HDIM + g0];
    const double go = g_s[r][24 + jj] + (double)b_ih[3 * HDIM + g0] + (double)b_hh[3 * HDIM + g0];
    const size_t oidx = (size_t)(r0 + r) * HDIM + g0;
    const double cold = (t == 0) ? 0.0 : cst[oidx];
    const double cn = sigd(gf) * cold + sigd(gi) * tanh(gg);
    const double hn = sigd(go) * tanh(cn);
    cst[oidx] = cn;
    hW[oidx]  = hn;
  }
}

// Phase 2: 64 blocks x 4 batch rows; weight loads amortized over the 4 rows.
__global__ __launch_bounds__(256) void k_phase2(
    const double* __restrict__ h, const float* __restrict__ wtro,
    const float* __restrict__ b_out, const float* __restrict__ wtrc,
    const float* __restrict__ b_ctrl, const float* __restrict__ noise,
    const int* __restrict__ epoch_p, double* __restrict__ ybar,
    double* __restrict__ preds, float* __restrict__ halt,
    double* __restrict__ ylast, int* __restrict__ rowlive,
    int* __restrict__ alive, int t)
{
  if (t > 0 && alive[t - 1] == 0) return;

  const int tid = threadIdx.x;
  const int b0  = blockIdx.x * 4;

  bool lv[4];
  #pragma unroll
  for (int r = 0; r < 4; ++r)
    lv[r] = (t == 0) || (rowlive[b0 + r] != 0);
  if (!(lv[0] | lv[1] | lv[2] | lv[3])) return;

  __shared__ double hsh[4][HDIM];      // 16 KB
  __shared__ double pO[4][4][64];      //  8 KB  [kq][row][c]
  __shared__ double pC[4][4][64];      //  8 KB
  __shared__ double ysh[4][64];        //  2 KB

  #pragma unroll
  for (int r = 0; r < 4; ++r)
    *(double2*)&hsh[r][2 * tid] =
        *(const double2*)(h + (size_t)(b0 + r) * HDIM + 2 * tid);
  __syncthreads();

  const int c = tid & 63, kq = tid >> 6;
  const int k0 = kq * 128;

  double sO[4] = {0, 0, 0, 0}, sC[4] = {0, 0, 0, 0};
  #pragma unroll 4
  for (int k = k0; k < k0 + 128; ++k) {
    const double wO = (double)wtro[k * 64 + c];
    const double wC = (double)wtrc[k * 64 + c];
    #pragma unroll
    for (int r = 0; r < 4; ++r) {
      sO[r] += hsh[r][k] * wO;
      sC[r] += hsh[r][k] * wC;
    }
  }
  #pragma unroll
  for (int r = 0; r < 4; ++r) { pO[kq][r][c] = sO[r]; pC[kq][r][c] = sC[r]; }
  __syncthreads();

  {  // y_hat for (row = tid>>6, c = tid&63)
    const int r = kq;
    ysh[r][c] = sigd(pO[0][r][c] + pO[1][r][c] + pO[2][r][c] + pO[3][r][c]
                     + (double)b_out[c]);
  }
  __syncthreads();

  {  // controller + halting, wave r handles row b0+r
    const int r = kq;
    const int b = b0 + r;
    double a2 = pC[0][r][c] + pC[1][r][c] + pC[2][r][c] + pC[3][r][c];
    #pragma unroll 8
    for (int j = 0; j < CDIM; ++j)
      a2 += ysh[r][j] * (double)wtrc[(512 + j) * 64 + c];
    a2 += (double)t * (double)wtrc[576 * 64 + c] + (double)b_ctrl[c];

    bool pz = false;
    if (lv[r]) {
      const double eps = exp(-7.0 * (double)(*epoch_p) / 99.0);
      const double pr  = (1.0 - eps) * sigd(a2) + eps * 0.05;
      const double n   = (double)noise[((size_t)t * BBATCH + b) * CDIM + c];
      const bool   at  = n < pr;
      const double yh  = ysh[r][c];
      const size_t i   = (size_t)b * CDIM + c;

      const double pred_old = (t == 0) ? 0.0  : preds[i];
      const double ybar_old = (t == 0) ? 0.0  : ybar[i];
      const float  halt_old = (t == 0) ? -1.0f : halt[i];

      const double pred_new = (at && pred_old == 0.0) ? yh : pred_old;
      preds[i] = pred_new;
      ybar[i]  = (at && ybar_old == 0.0) ? 1.0 : ybar_old;
      halt[i]  = (halt_old == -1.0f && at) ? (float)t : halt_old;
      ylast[i] = yh;
      pz = (pred_new == 0.0);
    }
    const unsigned long long m = __ballot(pz);
    if (c == 0 && lv[r]) {
      rowlive[b] = (m != 0ull) ? 1 : 0;
      if (m != 0ull) atomicOr(alive + t, 1);
    }
  }
}

__global__ __launch_bounds__(256) void k_final_out(
    const double* __restrict__ preds, const double* __restrict__ ylast,
    float* __restrict__ out)
{
  const int i = blockIdx.x * 256 + threadIdx.x;
  const double p = preds[i];
  out[i] = (float)(p == 0.0 ? ylast[i] : p);
}

__global__ __launch_bounds__(256) void k_final_mean(
    const float* __restrict__ halt, float* __restrict__ out)
{
  __shared__ double s[256];
  double acc = 0.0;
  for (int i = threadIdx.x; i < BBATCH * CDIM; i += 256) {
    const float hp = halt[i];
    acc += 1.0 + (hp == -1.0f ? (double)(TT - 1) : (double)hp);
  }
  s[threadIdx.x] = acc;
  __syncthreads();
  for (int off = 128; off > 0; off >>= 1) {
    if (threadIdx.x < off) s[threadIdx.x] += s[threadIdx.x + off];
    __syncthreads();
  }
  if (threadIdx.x == 0)
    out[BBATCH * CDIM] = (float)(s[0] / (double)(BBATCH * CDIM) / (double)(TT + 1));
}

extern "C" void kernel_launch(void* const* d_in, const int* in_sizes, int n_in,
                              void* d_out, int out_size, void* d_ws, size_t ws_size,
                              hipStream_t stream)
{
  const float* X      = (const float*)d_in[0];
  const float* noise  = (const float*)d_in[1];
  const float* W_ih   = (const float*)d_in[2];
  const float* W_hh   = (const float*)d_in[3];
  const float* b_ih   = (const float*)d_in[4];
  const float* b_hh   = (const float*)d_in[5];
  const float* W_out  = (const float*)d_in[6];
  const float* b_out  = (const float*)d_in[7];
  const float* W_ctrl = (const float*)d_in[8];
  const float* b_ctrl = (const float*)d_in[9];
  const int*   epoch  = (const int*)d_in[10];
  float* out = (float*)d_out;

  char* ws = (char*)d_ws;
  double* h0      = (double*)ws;
  double* h1      = h0    + (size_t)BBATCH * HDIM;
  double* cst     = h1    + (size_t)BBATCH * HDIM;
  double* ybar    = cst   + (size_t)BBATCH * HDIM;
  double* preds   = ybar  + (size_t)BBATCH * CDIM;
  double* ylast   = preds + (size_t)BBATCH * CDIM;
  float*  halt    = (float*)(ylast + (size_t)BBATCH * CDIM);
  float*  wtro    = halt + (size_t)BBATCH * CDIM;
  float*  wtrc    = wtro + (size_t)HDIM * CDIM;
  int*    rowlive = (int*)(wtrc + (size_t)577 * CDIM);
  int*    alive   = rowlive + BBATCH;

  k_init<<<145, 256, 0, stream>>>(wtro, W_out, wtrc, W_ctrl, rowlive, alive);

  for (int t = 0; t < TT; ++t) {
    const double* hR = (t & 1) ? h1 : h0;
    double*       hW = (t & 1) ? h0 : h1;
    k_phase1<<<dim3(64, 8), 256, 0, stream>>>(X, W_ih, W_hh, b_ih, b_hh,
                                              hR, hW, cst, ybar, rowlive, alive, t);
    k_phase2<<<64, 256, 0, stream>>>(hW, wtro, b_out, wtrc, b_ctrl, noise,
                                     epoch, ybar, preds, halt, ylast,
                                     rowlive, alive, t);
  }

  k_final_out<<<64, 256, 0, stream>>>(preds, ylast, out);
  k_final_mean<<<1, 256, 0, stream>>>(halt, out);
}

// Round 8
// 4646.108 us; speedup vs baseline: 1.0766x; 1.0766x over previous
//
#include <hip/hip_runtime.h>
#include <math.h>

#define TT 400
#define BBATCH 256
#define VDIM 128
#define CDIM 64
#define HDIM 512
#define KB 32
#define NCHUNK 22

typedef double d4 __attribute__((ext_vector_type(4)));

__device__ __forceinline__ double sigd(double x) {
  if (x >= 0.0) { double e = exp(-x); return 1.0 / (1.0 + e); }
  double e = exp(x); return e / (1.0 + e);
}

// transpose W_out/W_ctrl to [k][c]; init rowlive/alive. All other state is
// (re)initialized inside the step kernels via t==0 guards.
__global__ __launch_bounds__(256) void k_init(
    float* __restrict__ wtro, const float* __restrict__ W_out,
    float* __restrict__ wtrc, const float* __restrict__ W_ctrl,
    int* __restrict__ rowlive, int* __restrict__ alive)
{
  const int i = blockIdx.x * 256 + threadIdx.x;
  if (i < HDIM * CDIM) {
    const int k = i >> 6, c = i & 63;
    wtro[i] = W_out[c * HDIM + k];
  }
  if (i < 577 * CDIM) {
    const int k = i >> 6, c = i & 63;
    wtrc[i] = W_ctrl[c * 577 + k];
  }
  if (i < BBATCH) rowlive[i] = 1;
  if (i < TT) alive[i] = 0;
}

// Phase 1: gates GEMM (f64 MFMA) + fused LSTM cell.
// Grid (64, 8): 64 col-blocks (8 hidden x 4 gates) x 8 row-blocks of 32 rows.
// 3-buffer LDS ring + depth-2 register prefetch: chunk ci+2 loads issue while
// chunk ci computes, so global latency has ~2 chunk-times to land.
__global__ __launch_bounds__(256) void k_phase1(
    const float* __restrict__ X, const float* __restrict__ W_ih,
    const float* __restrict__ W_hh, const float* __restrict__ b_ih,
    const float* __restrict__ b_hh, const double* __restrict__ hR,
    double* __restrict__ hW, double* __restrict__ cst,
    const double* __restrict__ ybar, const int* __restrict__ rowlive,
    const int* __restrict__ alive, int t)
{
  if (t > 0 && alive[t - 1] == 0) return;      // everything halted: dead step

  const int tid  = threadIdx.x;
  const int lane = tid & 63;
  const int wid  = tid >> 6;
  const int cb   = blockIdx.x;
  const int rb   = blockIdx.y;
  const int r0   = rb * 32;
  const int hbase = cb * 8;

  // 32-row block skip: all rows halted -> no output of this block is ever read
  if (t > 0) {
    const unsigned long long m =
        __ballot((lane < 32) && (rowlive[r0 + (lane & 31)] != 0));
    if (m == 0ull) return;
  }

  // fragment staging; k-slot stride padded 64->66 to break write bank conflicts
  __shared__ __align__(16) double aF[3][2][8][66];   // 25.3 KB
  __shared__ __align__(16) double bF[3][2][8][66];   // 25.3 KB
  __shared__ __align__(16) double g_s[32][33];       //  8.4 KB

  const int sk  = (tid & 7) * 4;    // k offset within chunk
  const int sr  = tid >> 3;         // 0..31: A-row / B-col
  const int s   = tid & 7;          // k-slot
  const int srt = sr >> 4, srr = sr & 15;
  const int wg  = (sr >> 3) * HDIM + hbase + (sr & 7);  // W row for col sr

  // Empirical f64-MFMA D-layout probe: A[i][0]=i+1,A[i][1]=1,B[0][j]=1,
  // B[1][j]=1000(j+1) => D[i][j]=(i+1)+1000(j+1); decode reg->row/col.
  int rowm[4], colm[4];
  {
    d4 dp = {0.0, 0.0, 0.0, 0.0};
    const double ap = (lane < 16) ? (double)(lane + 1) : (lane < 32 ? 1.0 : 0.0);
    const double bp = (lane < 16) ? 1.0
                    : (lane < 32 ? 1000.0 * (double)((lane & 15) + 1) : 0.0);
    dp = __builtin_amdgcn_mfma_f64_16x16x4f64(ap, bp, dp, 0, 0, 0);
    #pragma unroll
    for (int r = 0; r < 4; ++r) {
      const int iv = (int)(dp[r] + 0.5);
      rowm[r] = ((iv % 1000) - 1) & 15;
      colm[r] = ((iv / 1000) - 1) & 15;
    }
  }

  // two named register prefetch sets (compile-time indexed, no scratch)
  double paA[4], paB[4];
  float  pwA[4], pwB[4];

  auto load_to = [&](int ci, double* pa, float* pw) {
    const int kk = ci * KB + sk;
    const int rr = r0 + sr;
    if (kk < VDIM) {
      const float4 v = *(const float4*)(X + ((size_t)t * BBATCH + rr) * VDIM + kk);
      pa[0] = v.x; pa[1] = v.y; pa[2] = v.z; pa[3] = v.w;
    } else if (t == 0) {
      pa[0] = 0.0; pa[1] = 0.0; pa[2] = 0.0; pa[3] = 0.0;
    } else if (kk < VDIM + CDIM) {
      const double2 v0 = *(const double2*)(ybar + (size_t)rr * CDIM + (kk - VDIM));
      const double2 v1 = *(const double2*)(ybar + (size_t)rr * CDIM + (kk - VDIM) + 2);
      pa[0] = v0.x; pa[1] = v0.y; pa[2] = v1.x; pa[3] = v1.y;
    } else {
      const double2 v0 = *(const double2*)(hR + (size_t)rr * HDIM + (kk - 192));
      const double2 v1 = *(const double2*)(hR + (size_t)rr * HDIM + (kk - 192) + 2);
      pa[0] = v0.x; pa[1] = v0.y; pa[2] = v1.x; pa[3] = v1.y;
    }
    const float4 wv = (kk < 192)
      ? *(const float4*)(W_ih + (size_t)wg * 192 + kk)
      : *(const float4*)(W_hh + (size_t)wg * HDIM + (kk - 192));
    pw[0] = wv.x; pw[1] = wv.y; pw[2] = wv.z; pw[3] = wv.w;
  };
  auto store_to = [&](int buf, const double* pa, const float* pw) {
    #pragma unroll
    for (int j = 0; j < 4; ++j)
      aF[buf][srt][s][16 * j + srr] = pa[j];
    #pragma unroll
    for (int j = 0; j < 4; ++j)
      bF[buf][srt][s][16 * j + srr] = (double)pw[j];
  };

  const int rt = wid >> 1, ct = wid & 1;   // wave's 16x16 output tile
  d4 aa = {0.0, 0.0, 0.0, 0.0}, ab = aa;

  auto mfma_chunk = [&](int buf) {
    #pragma unroll
    for (int ss = 0; ss < 8; ++ss) {
      const double av = aF[buf][rt][ss][lane];
      const double bv = bF[buf][ct][ss][lane];
      if (ss & 1) ab = __builtin_amdgcn_mfma_f64_16x16x4f64(av, bv, ab, 0, 0, 0);
      else        aa = __builtin_amdgcn_mfma_f64_16x16x4f64(av, bv, aa, 0, 0, 0);
    }
  };

  // prologue: chunk0 staged; chunk1 in regs (set B)
  load_to(0, paA, pwA);
  store_to(0, paA, pwA);
  load_to(1, paB, pwB);
  __syncthreads();

  // 2-unrolled main loop, depth-2 prefetch, one barrier per chunk.
  // even chunk k:   load k+2 -> A | mfma buf[k%3]     | store k+1 (B) -> buf[(k+1)%3]
  // odd  chunk k+1: load k+3 -> B | mfma buf[(k+1)%3] | store k+2 (A) -> buf[(k+2)%3]
  for (int k = 0; k < NCHUNK; k += 2) {
    if (k + 2 < NCHUNK) load_to(k + 2, paA, pwA);
    mfma_chunk(k % 3);
    store_to((k + 1) % 3, paB, pwB);
    __syncthreads();

    if (k + 3 < NCHUNK) load_to(k + 3, paB, pwB);
    mfma_chunk((k + 1) % 3);
    if (k + 2 < NCHUNK) store_to((k + 2) % 3, paA, pwA);
    __syncthreads();
  }
  const d4 acc = aa + ab;

  #pragma unroll
  for (int r = 0; r < 4; ++r)
    g_s[16 * rt + rowm[r]][16 * ct + colm[r]] = acc[r];
  __syncthreads();

  // LSTM cell: 32 rows x 8 hidden = 256 pairs, 1/thread; 8 consecutive lanes
  // = 8 consecutive hidden units -> 64B-contiguous global accesses.
  {
    const int jj = tid & 7, r = tid >> 3;
    const int g0 = hbase + jj;
    const double gi = g_s[r][jj]      + (double)b_ih[0 * HDIM + g0] + (double)b_hh[0 * HDIM + g0];
    const double gf = g_s[r][8 + jj]  + (double)b_ih[1 * HDIM + g0] + (double)b_hh[1 * HDIM + g0];
    const double gg = g_s[r][16 + jj] + (double)b_ih[2 * HDIM + g0] + (double)b_hh[2 * HDIM + g0];
    const double go = g_s[r][24 + jj] + (double)b_ih[3 * HDIM + g0] + (double)b_hh[3 * HDIM + g0];
    const size_t oidx = (size_t)(r0 + r) * HDIM + g0;
    const double cold = (t == 0) ? 0.0 : cst[oidx];
    const double cn = sigd(gf) * cold + sigd(gi) * tanh(gg);
    const double hn = sigd(go) * tanh(cn);
    cst[oidx] = cn;
    hW[oidx]  = hn;
  }
}

// Phase 2: one batch row per block; fused dual GEMV; row-level skip.
__global__ __launch_bounds__(256) void k_phase2(
    const double* __restrict__ h, const float* __restrict__ wtro,
    const float* __restrict__ b_out, const float* __restrict__ wtrc,
    const float* __restrict__ b_ctrl, const float* __restrict__ noise,
    const int* __restrict__ epoch_p, double* __restrict__ ybar,
    double* __restrict__ preds, float* __restrict__ halt,
    double* __restrict__ ylast, int* __restrict__ rowlive,
    int* __restrict__ alive, int t)
{
  const int tid = threadIdx.x;
  const int b   = blockIdx.x;
  if (t > 0 && rowlive[b] == 0) return;

  __shared__ double hsh[HDIM];
  __shared__ double p1[4][64];
  __shared__ double p2[4][64];
  __shared__ double ysh[64];

  *(double2*)&hsh[2 * tid] = *(const double2*)(h + (size_t)b * HDIM + 2 * tid);
  __syncthreads();

  const int c = tid & 63, kq = tid >> 6;
  const int k0 = kq * 128;

  double s1 = 0.0, s2 = 0.0;
  #pragma unroll 8
  for (int k = k0; k < k0 + 128; ++k) {
    const double hk = hsh[k];
    s1 += hk * (double)wtro[k * 64 + c];
    s2 += hk * (double)wtrc[k * 64 + c];
  }
  p1[kq][c] = s1;
  p2[kq][c] = s2;
  __syncthreads();

  if (tid < 64)
    ysh[tid] = sigd(p1[0][tid] + p1[1][tid] + p1[2][tid] + p1[3][tid]
                    + (double)b_out[tid]);
  __syncthreads();

  if (tid < 64) {
    double a2 = p2[0][tid] + p2[1][tid] + p2[2][tid] + p2[3][tid];
    #pragma unroll 8
    for (int j = 0; j < CDIM; ++j)
      a2 += ysh[j] * (double)wtrc[(512 + j) * 64 + tid];
    a2 += (double)t * (double)wtrc[576 * 64 + tid] + (double)b_ctrl[tid];

    const double eps = exp(-7.0 * (double)(*epoch_p) / 99.0);
    const double pr  = (1.0 - eps) * sigd(a2) + eps * 0.05;
    const double n   = (double)noise[((size_t)t * BBATCH + b) * CDIM + tid];
    const bool   at  = n < pr;
    const double yh  = ysh[tid];
    const size_t i   = (size_t)b * CDIM + tid;

    const double pred_old = (t == 0) ? 0.0  : preds[i];
    const double ybar_old = (t == 0) ? 0.0  : ybar[i];
    const float  halt_old = (t == 0) ? -1.0f : halt[i];

    const double pred_new = (at && pred_old == 0.0) ? yh : pred_old;
    preds[i] = pred_new;
    ybar[i]  = (at && ybar_old == 0.0) ? 1.0 : ybar_old;
    halt[i]  = (halt_old == -1.0f && at) ? (float)t : halt_old;
    ylast[i] = yh;

    const unsigned long long m = __ballot(pred_new == 0.0);
    if (tid == 0) {
      rowlive[b] = (m != 0ull) ? 1 : 0;
      if (m != 0ull) atomicOr(alive + t, 1);
    }
  }
}

__global__ __launch_bounds__(256) void k_final_out(
    const double* __restrict__ preds, const double* __restrict__ ylast,
    float* __restrict__ out)
{
  const int i = blockIdx.x * 256 + threadIdx.x;
  const double p = preds[i];
  out[i] = (float)(p == 0.0 ? ylast[i] : p);
}

__global__ __launch_bounds__(256) void k_final_mean(
    const float* __restrict__ halt, float* __restrict__ out)
{
  __shared__ double s[256];
  double acc = 0.0;
  for (int i = threadIdx.x; i < BBATCH * CDIM; i += 256) {
    const float hp = halt[i];
    acc += 1.0 + (hp == -1.0f ? (double)(TT - 1) : (double)hp);
  }
  s[threadIdx.x] = acc;
  __syncthreads();
  for (int off = 128; off > 0; off >>= 1) {
    if (threadIdx.x < off) s[threadIdx.x] += s[threadIdx.x + off];
    __syncthreads();
  }
  if (threadIdx.x == 0)
    out[BBATCH * CDIM] = (float)(s[0] / (double)(BBATCH * CDIM) / (double)(TT + 1));
}

extern "C" void kernel_launch(void* const* d_in, const int* in_sizes, int n_in,
                              void* d_out, int out_size, void* d_ws, size_t ws_size,
                              hipStream_t stream)
{
  const float* X      = (const float*)d_in[0];
  const float* noise  = (const float*)d_in[1];
  const float* W_ih   = (const float*)d_in[2];
  const float* W_hh   = (const float*)d_in[3];
  const float* b_ih   = (const float*)d_in[4];
  const float* b_hh   = (const float*)d_in[5];
  const float* W_out  = (const float*)d_in[6];
  const float* b_out  = (const float*)d_in[7];
  const float* W_ctrl = (const float*)d_in[8];
  const float* b_ctrl = (const float*)d_in[9];
  const int*   epoch  = (const int*)d_in[10];
  float* out = (float*)d_out;

  char* ws = (char*)d_ws;
  double* h0      = (double*)ws;
  double* h1      = h0    + (size_t)BBATCH * HDIM;
  double* cst     = h1    + (size_t)BBATCH * HDIM;
  double* ybar    = cst   + (size_t)BBATCH * HDIM;
  double* preds   = ybar  + (size_t)BBATCH * CDIM;
  double* ylast   = preds + (size_t)BBATCH * CDIM;
  float*  halt    = (float*)(ylast + (size_t)BBATCH * CDIM);
  float*  wtro    = halt + (size_t)BBATCH * CDIM;
  float*  wtrc    = wtro + (size_t)HDIM * CDIM;
  int*    rowlive = (int*)(wtrc + (size_t)577 * CDIM);
  int*    alive   = rowlive + BBATCH;

  k_init<<<145, 256, 0, stream>>>(wtro, W_out, wtrc, W_ctrl, rowlive, alive);

  for (int t = 0; t < TT; ++t) {
    const double* hR = (t & 1) ? h1 : h0;
    double*       hW = (t & 1) ? h0 : h1;
    k_phase1<<<dim3(64, 8), 256, 0, stream>>>(X, W_ih, W_hh, b_ih, b_hh,
                                              hR, hW, cst, ybar, rowlive, alive, t);
    k_phase2<<<BBATCH, 256, 0, stream>>>(hW, wtro, b_out, wtrc, b_ctrl, noise,
                                         epoch, ybar, preds, halt, ylast,
                                         rowlive, alive, t);
  }

  k_final_out<<<64, 256, 0, stream>>>(preds, ylast, out);
  k_final_mean<<<1, 256, 0, stream>>>(halt, out);
}

// Round 9
// 4211.087 us; speedup vs baseline: 1.1879x; 1.1033x over previous
//
#include <hip/hip_runtime.h>
#include <math.h>

#define TT 400
#define BBATCH 256
#define VDIM 128
#define CDIM 64
#define HDIM 512
#define NCHUNK 11   // 11 rounds x 64 k (2 k-halves of 32)

typedef double d4 __attribute__((ext_vector_type(4)));

__device__ __forceinline__ double sigd(double x) {
  if (x >= 0.0) { double e = exp(-x); return 1.0 / (1.0 + e); }
  double e = exp(x); return e / (1.0 + e);
}

// transpose W_out/W_ctrl to [k][c]; init rowlive/alive. All other state is
// (re)initialized inside the step kernels via t==0 guards.
__global__ __launch_bounds__(256) void k_init(
    float* __restrict__ wtro, const float* __restrict__ W_out,
    float* __restrict__ wtrc, const float* __restrict__ W_ctrl,
    int* __restrict__ rowlive, int* __restrict__ alive)
{
  const int i = blockIdx.x * 256 + threadIdx.x;
  if (i < HDIM * CDIM) {
    const int k = i >> 6, c = i & 63;
    wtro[i] = W_out[c * HDIM + k];
  }
  if (i < 577 * CDIM) {
    const int k = i >> 6, c = i & 63;
    wtrc[i] = W_ctrl[c * 577 + k];
  }
  if (i < BBATCH) rowlive[i] = 1;
  if (i < TT) alive[i] = 0;
}

// Phase 1: gates GEMM (f64 MFMA) + fused LSTM cell.
// Grid (64,16): 64 col-blocks (32 gate-cols) x 16 row-blocks (16 rows).
// 4 waves = (ct in {0,1}) x (kh in {0,1}) : 2 col-tiles x 2 k-halves.
// ~33.5 KB LDS -> 4 blocks/CU -> 4 waves/SIMD, each from a different block
// (barrier-decoupled) so the f64 MFMA pipe stays fed through staging stalls.
__global__ __launch_bounds__(256, 4) void k_phase1(
    const float* __restrict__ X, const float* __restrict__ W_ih,
    const float* __restrict__ W_hh, const float* __restrict__ b_ih,
    const float* __restrict__ b_hh, const double* __restrict__ hR,
    double* __restrict__ hW, double* __restrict__ cst,
    const double* __restrict__ ybar, const int* __restrict__ rowlive,
    const int* __restrict__ alive, int t)
{
  if (t > 0 && alive[t - 1] == 0) return;      // everything halted: dead step

  const int tid  = threadIdx.x;
  const int lane = tid & 63;
  const int wid  = tid >> 6;
  const int cb   = blockIdx.x;
  const int rb   = blockIdx.y;
  const int r0   = rb * 16;
  const int hbase = cb * 8;

  // 16-row block skip: all rows halted -> outputs never read
  if (t > 0) {
    const unsigned long long m =
        __ballot((lane < 16) && (rowlive[r0 + (lane & 15)] != 0));
    if (m == 0ull) return;
  }

  // A fragments f64: [buf][kh][slot][16*j + row]  (pad 66; both sides conflict-free)
  // B fragments f32: [buf][kh][ct][slot][col*4 + j] (pad 68; b128 writes, <=2-way reads)
  __shared__ __align__(16) double aF[2][2][8][66];      // 16.9 KB
  __shared__ __align__(16) float  bF[2][2][2][8][68];   // 17.4 KB
  double* gsp = &aF[0][0][0][0];   // gate staging aliases aF after the k-loop

  const int sA  = tid & 7;          // k-slot
  const int khA = (tid >> 3) & 1;   // k-half
  const int rrA = tid >> 4;         // 0..15: A row / B col

  // Empirical f64-MFMA D-layout probe: A[i][0]=i+1,A[i][1]=1,B[0][j]=1,
  // B[1][j]=1000(j+1) => D[i][j]=(i+1)+1000(j+1); decode reg->row/col.
  int rowm[4], colm[4];
  {
    d4 dp = {0.0, 0.0, 0.0, 0.0};
    const double ap = (lane < 16) ? (double)(lane + 1) : (lane < 32 ? 1.0 : 0.0);
    const double bp = (lane < 16) ? 1.0
                    : (lane < 32 ? 1000.0 * (double)((lane & 15) + 1) : 0.0);
    dp = __builtin_amdgcn_mfma_f64_16x16x4f64(ap, bp, dp, 0, 0, 0);
    #pragma unroll
    for (int r = 0; r < 4; ++r) {
      const int iv = (int)(dp[r] + 0.5);
      rowm[r] = ((iv % 1000) - 1) & 15;
      colm[r] = ((iv / 1000) - 1) & 15;
    }
  }

  double pa[4];
  float4 pw0, pw1;

  // W rows for this thread's two staged cols (ct=0: col rrA, ct=1: col 16+rrA)
  const int c0 = rrA, c1 = 16 + rrA;
  const int wg0 = (c0 >> 3) * HDIM + hbase + (c0 & 7);
  const int wg1 = (c1 >> 3) * HDIM + hbase + (c1 & 7);

  auto load_to = [&](int ci) {
    const int kk = ci * 64 + khA * 32 + sA * 4;
    const int rr = r0 + rrA;
    if (kk < VDIM) {
      const float4 v = *(const float4*)(X + ((size_t)t * BBATCH + rr) * VDIM + kk);
      pa[0] = v.x; pa[1] = v.y; pa[2] = v.z; pa[3] = v.w;
    } else if (t == 0) {
      pa[0] = 0.0; pa[1] = 0.0; pa[2] = 0.0; pa[3] = 0.0;
    } else if (kk < VDIM + CDIM) {
      const double2 v0 = *(const double2*)(ybar + (size_t)rr * CDIM + (kk - VDIM));
      const double2 v1 = *(const double2*)(ybar + (size_t)rr * CDIM + (kk - VDIM) + 2);
      pa[0] = v0.x; pa[1] = v0.y; pa[2] = v1.x; pa[3] = v1.y;
    } else {
      const double2 v0 = *(const double2*)(hR + (size_t)rr * HDIM + (kk - 192));
      const double2 v1 = *(const double2*)(hR + (size_t)rr * HDIM + (kk - 192) + 2);
      pa[0] = v0.x; pa[1] = v0.y; pa[2] = v1.x; pa[3] = v1.y;
    }
    pw0 = (kk < 192) ? *(const float4*)(W_ih + (size_t)wg0 * 192 + kk)
                     : *(const float4*)(W_hh + (size_t)wg0 * HDIM + (kk - 192));
    pw1 = (kk < 192) ? *(const float4*)(W_ih + (size_t)wg1 * 192 + kk)
                     : *(const float4*)(W_hh + (size_t)wg1 * HDIM + (kk - 192));
  };
  auto store_to = [&](int buf) {
    #pragma unroll
    for (int j = 0; j < 4; ++j)
      aF[buf][khA][sA][16 * j + rrA] = pa[j];
    *(float4*)&bF[buf][khA][0][sA][rrA * 4] = pw0;
    *(float4*)&bF[buf][khA][1][sA][rrA * 4] = pw1;
  };

  const int ct = wid & 1, kh = wid >> 1;   // wave role
  d4 aa = {0.0, 0.0, 0.0, 0.0}, ab = aa;

  load_to(0);
  store_to(0);
  __syncthreads();

  for (int ci = 0; ci < NCHUNK; ++ci) {
    const int p = ci & 1;
    if (ci + 1 < NCHUNK) load_to(ci + 1);
    #pragma unroll
    for (int ss = 0; ss < 8; ++ss) {
      const double av = aF[p][kh][ss][lane];
      const double bv = (double)bF[p][kh][ct][ss][(lane & 15) * 4 + (lane >> 4)];
      if (ss & 1) ab = __builtin_amdgcn_mfma_f64_16x16x4f64(av, bv, ab, 0, 0, 0);
      else        aa = __builtin_amdgcn_mfma_f64_16x16x4f64(av, bv, aa, 0, 0, 0);
    }
    if (ci + 1 < NCHUNK) store_to(p ^ 1);
    __syncthreads();
  }
  const d4 acc = aa + ab;

  // scatter via probed D layout into gsp[kh][row][col32] (stride 33)
  #pragma unroll
  for (int r = 0; r < 4; ++r)
    gsp[kh * 528 + rowm[r] * 33 + 16 * ct + colm[r]] = acc[r];
  __syncthreads();

  // LSTM cell: 16 rows x 8 hidden = 128 pairs; k-halves summed in fixed order.
  if (tid < 128) {
    const int jj = tid & 7, r = tid >> 3;
    const int g0 = hbase + jj;
    const double gi = gsp[r * 33 + jj]      + gsp[528 + r * 33 + jj]
                    + (double)b_ih[0 * HDIM + g0] + (double)b_hh[0 * HDIM + g0];
    const double gf = gsp[r * 33 + 8 + jj]  + gsp[528 + r * 33 + 8 + jj]
                    + (double)b_ih[1 * HDIM + g0] + (double)b_hh[1 * HDIM + g0];
    const double gg = gsp[r * 33 + 16 + jj] + gsp[528 + r * 33 + 16 + jj]
                    + (double)b_ih[2 * HDIM + g0] + (double)b_hh[2 * HDIM + g0];
    const double go = gsp[r * 33 + 24 + jj] + gsp[528 + r * 33 + 24 + jj]
                    + (double)b_ih[3 * HDIM + g0] + (double)b_hh[3 * HDIM + g0];
    const size_t oidx = (size_t)(r0 + r) * HDIM + g0;
    const double cold = (t == 0) ? 0.0 : cst[oidx];
    const double cn = sigd(gf) * cold + sigd(gi) * tanh(gg);
    const double hn = sigd(go) * tanh(cn);
    cst[oidx] = cn;
    hW[oidx]  = hn;
  }
}

// Phase 2: one batch row per block; fused dual GEMV; row-level skip.
__global__ __launch_bounds__(256) void k_phase2(
    const double* __restrict__ h, const float* __restrict__ wtro,
    const float* __restrict__ b_out, const float* __restrict__ wtrc,
    const float* __restrict__ b_ctrl, const float* __restrict__ noise,
    const int* __restrict__ epoch_p, double* __restrict__ ybar,
    double* __restrict__ preds, float* __restrict__ halt,
    double* __restrict__ ylast, int* __restrict__ rowlive,
    int* __restrict__ alive, int t)
{
  const int tid = threadIdx.x;
  const int b   = blockIdx.x;
  if (t > 0 && rowlive[b] == 0) return;

  __shared__ double hsh[HDIM];
  __shared__ double p1[4][64];
  __shared__ double p2[4][64];
  __shared__ double ysh[64];

  *(double2*)&hsh[2 * tid] = *(const double2*)(h + (size_t)b * HDIM + 2 * tid);
  __syncthreads();

  const int c = tid & 63, kq = tid >> 6;
  const int k0 = kq * 128;

  double s1 = 0.0, s2 = 0.0;
  #pragma unroll 8
  for (int k = k0; k < k0 + 128; ++k) {
    const double hk = hsh[k];
    s1 += hk * (double)wtro[k * 64 + c];
    s2 += hk * (double)wtrc[k * 64 + c];
  }
  p1[kq][c] = s1;
  p2[kq][c] = s2;
  __syncthreads();

  if (tid < 64)
    ysh[tid] = sigd(p1[0][tid] + p1[1][tid] + p1[2][tid] + p1[3][tid]
                    + (double)b_out[tid]);
  __syncthreads();

  if (tid < 64) {
    double a2 = p2[0][tid] + p2[1][tid] + p2[2][tid] + p2[3][tid];
    #pragma unroll 8
    for (int j = 0; j < CDIM; ++j)
      a2 += ysh[j] * (double)wtrc[(512 + j) * 64 + tid];
    a2 += (double)t * (double)wtrc[576 * 64 + tid] + (double)b_ctrl[tid];

    const double eps = exp(-7.0 * (double)(*epoch_p) / 99.0);
    const double pr  = (1.0 - eps) * sigd(a2) + eps * 0.05;
    const double n   = (double)noise[((size_t)t * BBATCH + b) * CDIM + tid];
    const bool   at  = n < pr;
    const double yh  = ysh[tid];
    const size_t i   = (size_t)b * CDIM + tid;

    const double pred_old = (t == 0) ? 0.0  : preds[i];
    const double ybar_old = (t == 0) ? 0.0  : ybar[i];
    const float  halt_old = (t == 0) ? -1.0f : halt[i];

    const double pred_new = (at && pred_old == 0.0) ? yh : pred_old;
    preds[i] = pred_new;
    ybar[i]  = (at && ybar_old == 0.0) ? 1.0 : ybar_old;
    halt[i]  = (halt_old == -1.0f && at) ? (float)t : halt_old;
    ylast[i] = yh;

    const unsigned long long m = __ballot(pred_new == 0.0);
    if (tid == 0) {
      rowlive[b] = (m != 0ull) ? 1 : 0;
      if (m != 0ull) atomicOr(alive + t, 1);
    }
  }
}

__global__ __launch_bounds__(256) void k_final_out(
    const double* __restrict__ preds, const double* __restrict__ ylast,
    float* __restrict__ out)
{
  const int i = blockIdx.x * 256 + threadIdx.x;
  const double p = preds[i];
  out[i] = (float)(p == 0.0 ? ylast[i] : p);
}

__global__ __launch_bounds__(256) void k_final_mean(
    const float* __restrict__ halt, float* __restrict__ out)
{
  __shared__ double s[256];
  double acc = 0.0;
  for (int i = threadIdx.x; i < BBATCH * CDIM; i += 256) {
    const float hp = halt[i];
    acc += 1.0 + (hp == -1.0f ? (double)(TT - 1) : (double)hp);
  }
  s[threadIdx.x] = acc;
  __syncthreads();
  for (int off = 128; off > 0; off >>= 1) {
    if (threadIdx.x < off) s[threadIdx.x] += s[threadIdx.x + off];
    __syncthreads();
  }
  if (threadIdx.x == 0)
    out[BBATCH * CDIM] = (float)(s[0] / (double)(BBATCH * CDIM) / (double)(TT + 1));
}

extern "C" void kernel_launch(void* const* d_in, const int* in_sizes, int n_in,
                              void* d_out, int out_size, void* d_ws, size_t ws_size,
                              hipStream_t stream)
{
  const float* X      = (const float*)d_in[0];
  const float* noise  = (const float*)d_in[1];
  const float* W_ih   = (const float*)d_in[2];
  const float* W_hh   = (const float*)d_in[3];
  const float* b_ih   = (const float*)d_in[4];
  const float* b_hh   = (const float*)d_in[5];
  const float* W_out  = (const float*)d_in[6];
  const float* b_out  = (const float*)d_in[7];
  const float* W_ctrl = (const float*)d_in[8];
  const float* b_ctrl = (const float*)d_in[9];
  const int*   epoch  = (const int*)d_in[10];
  float* out = (float*)d_out;

  char* ws = (char*)d_ws;
  double* h0      = (double*)ws;
  double* h1      = h0    + (size_t)BBATCH * HDIM;
  double* cst     = h1    + (size_t)BBATCH * HDIM;
  double* ybar    = cst   + (size_t)BBATCH * HDIM;
  double* preds   = ybar  + (size_t)BBATCH * CDIM;
  double* ylast   = preds + (size_t)BBATCH * CDIM;
  float*  halt    = (float*)(ylast + (size_t)BBATCH * CDIM);
  float*  wtro    = halt + (size_t)BBATCH * CDIM;
  float*  wtrc    = wtro + (size_t)HDIM * CDIM;
  int*    rowlive = (int*)(wtrc + (size_t)577 * CDIM);
  int*    alive   = rowlive + BBATCH;

  k_init<<<145, 256, 0, stream>>>(wtro, W_out, wtrc, W_ctrl, rowlive, alive);

  for (int t = 0; t < TT; ++t) {
    const double* hR = (t & 1) ? h1 : h0;
    double*       hW = (t & 1) ? h0 : h1;
    k_phase1<<<dim3(64, 16), 256, 0, stream>>>(X, W_ih, W_hh, b_ih, b_hh,
                                               hR, hW, cst, ybar, rowlive, alive, t);
    k_phase2<<<BBATCH, 256, 0, stream>>>(hW, wtro, b_out, wtrc, b_ctrl, noise,
                                         epoch, ybar, preds, halt, ylast,
                                         rowlive, alive, t);
  }

  k_final_out<<<64, 256, 0, stream>>>(preds, ylast, out);
  k_final_mean<<<1, 256, 0, stream>>>(halt, out);
}